// Round 12
// baseline (419.948 us; speedup 1.0000x reference)
//
#include <hip/hip_runtime.h>

// B(derived), IN_DIM=784, NUM_NETS=30, N_NODES=20, NUM_OUT=10, DIM_OUT=16, NUM_ITER=3
// Validated: size-based binding; dtype detection; k1m MFMA; k2s; k3 routing math (k3y).
// R12 (k3z): priors stream diet — rwt as bf16 (exact for bf16-grade inputs),
// G=2 batches/block amortizes rwt reads (3.1GB -> 786MB L2), u via wave-uniform
// scalar loads (no LDS staging). VGPR capped via __launch_bounds__(160,4).
// ws: h1u[B*600] f32 | rwb[96000] bf16 | b1f[640] f32 | flags[8] | Wt[640*800] bf16 | xb[B*800] bf16

typedef unsigned short bfu;
typedef unsigned int u32;
typedef __attribute__((ext_vector_type(8))) short short8;
typedef __attribute__((ext_vector_type(4))) float floatx4;

__device__ __forceinline__ float bf2f(bfu u) { union { u32 i; float f; } v; v.i = ((u32)u) << 16; return v.f; }
__device__ __forceinline__ float lo2f(u32 w) { union { u32 i; float f; } v; v.i = w << 16; return v.f; }
__device__ __forceinline__ float hi2f(u32 w) { union { u32 i; float f; } v; v.i = w & 0xffff0000u; return v.f; }
__device__ __forceinline__ float ldf(const void* p, int idx, bool b16) {
    return b16 ? bf2f(((const bfu*)p)[idx]) : ((const float*)p)[idx];
}
__device__ __forceinline__ bfu f2bf(float f) {   // RNE
    u32 u = __float_as_uint(f);
    return (bfu)((u + 0x7FFFu + ((u >> 16) & 1u)) >> 16);
}

// ---- dtype detector (validated) ----
__global__ void detect_dtype(const u32* x, const u32* W1, const u32* b1,
                             const u32* W2, const u32* b2, const u32* rw,
                             u32* flags) {
    int t = threadIdx.x;
    if (t >= 6) return;
    const u32* p = (t == 0) ? x : (t == 1) ? W1 : (t == 2) ? b1
                 : (t == 3) ? W2 : (t == 4) ? b2 : rw;
    int c = 0;
    for (int i = 0; i < 64; i++) {
        u32 e = (p[i] >> 7) & 0xFF;
        c += (e >= 64 && e <= 140) ? 1 : 0;
    }
    flags[t] = (c >= 48) ? 1u : 0u;
}

// ---- prep: x -> xb[B][800] bf16 (validated) ----
__global__ void prep_xb(const void* x, bfu* __restrict__ xb, const u32* flags, int total) {
    const bool b16 = flags[0] != 0;
    int idx = blockIdx.x * 256 + threadIdx.x;
    if (idx >= total) return;
    int b = idx / 800, kk = idx - b * 800;
    bfu v = 0;
    if (kk < 784) {
        int src = b * 784 + kk;
        v = b16 ? ((const bfu*)x)[src] : f2bf(((const float*)x)[src]);
    }
    xb[idx] = v;
}

// ---- prep: W1[n][k][o] -> Wt[c][k] bf16 (validated) ----
__global__ void prep_wt(const void* W1, bfu* __restrict__ Wt, const u32* flags) {
    const bool wb = flags[1] != 0;
    int idx = blockIdx.x * 256 + threadIdx.x;
    if (idx >= 640 * 800) return;
    int c = idx / 800, k = idx - c * 800;
    bfu v = 0;
    if (c < 600 && k < 784) {
        int nn = c / 20, o = c - nn * 20;
        int src = nn * 15680 + k * 20 + o;
        v = wb ? ((const bfu*)W1)[src] : f2bf(((const float*)W1)[src]);
    }
    Wt[idx] = v;
}

// ---- prep: b1 -> fp32[640] (validated) ----
__global__ void prep_b1(const void* b1, float* __restrict__ b1f, const u32* flags) {
    int i = threadIdx.x;
    if (i >= 640) return;
    b1f[i] = (i < 600) ? ldf(b1, i, flags[2] != 0) : 0.f;
}

// ---- prep: rw[o][n][d][k] -> rwb[o][n][k][d] bf16 (exact copy if source bf16) ----
__global__ void prep_rwb(const void* rw, bfu* __restrict__ rwb, const u32* flags) {
    const bool rb = flags[5] != 0;
    int idx = blockIdx.x * 256 + threadIdx.x;
    if (idx >= 96000) return;
    int d = idx % 20;
    int k = (idx / 20) % 16;
    int n = (idx / 320) % 30;
    int o = idx / 9600;
    int src = o * 9600 + n * 320 + d * 16 + k;
    rwb[idx] = rb ? ((const bfu*)rw)[src] : f2bf(((const float*)rw)[src]);
}

// ---------------- K1m: h1 = relu(xb @ Wt^T + b1), bf16 MFMA (validated) ----------------
__global__ __launch_bounds__(256, 4) void k1m(const bfu* __restrict__ xb, const bfu* __restrict__ Wt,
                                              const float* __restrict__ b1f,
                                              float* __restrict__ h1, int Btot) {
    __shared__ short As[128 * 40];
    __shared__ short Bs[64 * 40];
    const int tid = threadIdx.x;
    const int w = tid >> 6, lane = tid & 63;
    const int quad = lane >> 4, fl = lane & 15;
    const int m0 = blockIdx.x * 128, n0 = blockIdx.y * 64;

    floatx4 acc[2][4];
    #pragma unroll
    for (int mi = 0; mi < 2; mi++)
        #pragma unroll
        for (int ni = 0; ni < 4; ni++) acc[mi][ni] = (floatx4){0.f, 0.f, 0.f, 0.f};

    const int arow = tid >> 1, aseg = tid & 1;
    const int brow = tid >> 2, bseg = tid & 3;
    int agrow = m0 + arow; if (agrow >= Btot) agrow = Btot - 1;
    const bfu* abase = xb + (size_t)agrow * 800 + aseg * 16;
    const bfu* bbase = Wt + (size_t)(n0 + brow) * 800 + bseg * 8;

    for (int k0 = 0; k0 < 800; k0 += 32) {
        uint4 qa0 = *(const uint4*)(abase + k0);
        uint4 qa1 = *(const uint4*)(abase + k0 + 8);
        uint4 qb  = *(const uint4*)(bbase + k0);

        __syncthreads();
        *(uint4*)&As[arow * 40 + aseg * 16 + 0] = qa0;
        *(uint4*)&As[arow * 40 + aseg * 16 + 8] = qa1;
        *(uint4*)&Bs[brow * 40 + bseg * 8] = qb;
        __syncthreads();

        short8 af[2], bfr[4];
        #pragma unroll
        for (int mi = 0; mi < 2; mi++)
            af[mi] = *(const short8*)&As[(w * 32 + mi * 16 + fl) * 40 + quad * 8];
        #pragma unroll
        for (int ni = 0; ni < 4; ni++)
            bfr[ni] = *(const short8*)&Bs[(ni * 16 + fl) * 40 + quad * 8];
        #pragma unroll
        for (int mi = 0; mi < 2; mi++)
            #pragma unroll
            for (int ni = 0; ni < 4; ni++)
                acc[mi][ni] = __builtin_amdgcn_mfma_f32_16x16x32_bf16(af[mi], bfr[ni], acc[mi][ni], 0, 0, 0);
    }

    #pragma unroll
    for (int mi = 0; mi < 2; mi++) {
        #pragma unroll
        for (int ni = 0; ni < 4; ni++) {
            const int c = n0 + ni * 16 + fl;
            #pragma unroll
            for (int r = 0; r < 4; r++) {
                const int m = m0 + w * 32 + mi * 16 + quad * 4 + r;
                if (c < 600 && m < Btot)
                    h1[(size_t)m * 600 + c] = fmaxf(acc[mi][ni][r] + b1f[c], 0.f);
            }
        }
    }
}

// ---------------- K2s: u = squash(relu(h1 @ W2 + b2)), LDS-staged W2 (validated) ----------------
__global__ __launch_bounds__(256) void k2s(const float* h1, const void* W2, const void* b2,
                                           float* u, const u32* flags, int total) {
    __shared__ float W2s[12000];
    __shared__ float b2s[600];
    const bool wb = flags[3] != 0, bb = flags[4] != 0;
    const int tid = threadIdx.x;
    for (int i = tid; i < 12000; i += 256) W2s[i] = ldf(W2, i, wb);
    for (int i = tid; i < 600; i += 256) b2s[i] = ldf(b2, i, bb);
    __syncthreads();

    int t = blockIdx.x * 256 + tid;
    if (t >= total) return;          // t = b*30 + n
    const int b = t / 30, n = t - b * 30;
    const float* hp = h1 + (size_t)b * 600 + n * 20;
    float h[20];
    #pragma unroll
    for (int d4 = 0; d4 < 20; d4 += 4) {
        float4 v = *(const float4*)(hp + d4);
        h[d4] = v.x; h[d4 + 1] = v.y; h[d4 + 2] = v.z; h[d4 + 3] = v.w;
    }
    const float* wn = &W2s[n * 400];
    float o[20];
    float sq = 0.f;
    #pragma unroll
    for (int e = 0; e < 20; e++) {
        float acc = b2s[n * 20 + e];
        #pragma unroll
        for (int d = 0; d < 20; d++) acc += h[d] * wn[d * 20 + e];
        acc = fmaxf(acc, 0.f);
        o[e] = acc;
        sq += acc * acc;
    }
    float sc = (sq > 0.f) ? sqrtf(sq) / (1.f + sq) : 0.f;
    float* up = u + (size_t)b * 600 + n * 20;
    #pragma unroll
    for (int e4 = 0; e4 < 20; e4 += 4) {
        float4 v;
        v.x = o[e4] * sc; v.y = o[e4 + 1] * sc; v.z = o[e4 + 2] * sc; v.w = o[e4 + 3] * sc;
        *(float4*)(up + e4) = v;
    }
}

// ---------------- K3z: routing; 160 thr/block, 2 batches, bf16 rwt, scalar u loads ----------------
// Same routing math as validated k3y; priors loop re-economized.
__global__ __launch_bounds__(160, 4) void k3z(const float* __restrict__ u,
                                              const bfu* __restrict__ rwb,
                                              float* __restrict__ out, int Btot) {
    __shared__ float L[2][300];   // logits [g][n*10+o]
    __shared__ float P[2][300];   // softmax probs
    const int tid = threadIdx.x;  // 0..159
    const int o = tid >> 4, k = tid & 15;
    const int b0 = blockIdx.x * 2;
    const int bA = (b0 < Btot) ? b0 : Btot - 1;          // uniform
    const int bB = (b0 + 1 < Btot) ? b0 + 1 : Btot - 1;  // uniform

    const float* u0 = u + (size_t)bA * 600;   // wave-uniform addresses -> s_load
    const float* u1 = u + (size_t)bB * 600;

    // priors: pri[g][n] = sum_d rwb[o][n][k][d] * u[b_g][n][d]
    float pri[2][30];
    const bfu* rp = rwb + o * 9600 + k * 20;   // [o][n][k][d], 40B per (o,n,k), 8B-aligned
    #pragma unroll 2
    for (int n = 0; n < 30; n++) {
        const uint2* rq = (const uint2*)(rp + n * 320);
        float rv[20];
        #pragma unroll
        for (int j = 0; j < 5; j++) {
            uint2 w = rq[j];
            rv[j * 4 + 0] = lo2f(w.x); rv[j * 4 + 1] = hi2f(w.x);
            rv[j * 4 + 2] = lo2f(w.y); rv[j * 4 + 3] = hi2f(w.y);
        }
        float a0 = 0.f, a1 = 0.f;
        #pragma unroll
        for (int d = 0; d < 20; d++) {
            a0 += rv[d] * u0[n * 20 + d];
            a1 += rv[d] * u1[n * 20 + d];
        }
        pri[0][n] = a0; pri[1][n] = a1;
    }

    for (int i = tid; i < 600; i += 160) L[i / 300][i % 300] = 0.f;
    __syncthreads();

    float v[2];
    for (int it = 0; it < 3; it++) {
        // phase A: P[g][n][:] = softmax(L[g][n][:]) by tid<60 (g=tid/30, n=tid%30)
        if (tid < 60) {
            const int g = tid / 30, n = tid - (tid / 30) * 30;
            float mx = L[g][n * 10];
            #pragma unroll
            for (int oo = 1; oo < 10; oo++) mx = fmaxf(mx, L[g][n * 10 + oo]);
            float e[10], den = 0.f;
            #pragma unroll
            for (int oo = 0; oo < 10; oo++) { e[oo] = __expf(L[g][n * 10 + oo] - mx); den += e[oo]; }
            float inv = 1.f / den;
            #pragma unroll
            for (int oo = 0; oo < 10; oo++) P[g][n * 10 + oo] = e[oo] * inv;
        }
        __syncthreads();
        // phase B: s thread-local over n; squash over k (shfl-16)
        #pragma unroll
        for (int g = 0; g < 2; g++) {
            float s = 0.f;
            #pragma unroll
            for (int n = 0; n < 30; n++) s += P[g][n * 10 + o] * pri[g][n];
            float q = s * s;
            q += __shfl_xor(q, 1, 16);
            q += __shfl_xor(q, 2, 16);
            q += __shfl_xor(q, 4, 16);
            q += __shfl_xor(q, 8, 16);
            v[g] = s * sqrtf(q) / (1.f + q);
        }
        if (it < 2) {
            // phase C: L[g][n][o] += sum_k pri*v (shfl-16; k==0 lane writes)
            #pragma unroll
            for (int g = 0; g < 2; g++) {
                #pragma unroll 5
                for (int n = 0; n < 30; n++) {
                    float t = pri[g][n] * v[g];
                    t += __shfl_xor(t, 1, 16);
                    t += __shfl_xor(t, 2, 16);
                    t += __shfl_xor(t, 4, 16);
                    t += __shfl_xor(t, 8, 16);
                    if (k == 0) L[g][n * 10 + o] += t;
                }
            }
            __syncthreads();
        }
    }
    if (b0 < Btot)     out[(size_t)b0 * 160 + tid] = v[0];
    if (b0 + 1 < Btot) out[(size_t)(b0 + 1) * 160 + tid] = v[1];
}

extern "C" void kernel_launch(void* const* d_in, const int* in_sizes, int n_in,
                              void* d_out, int out_size, void* d_ws, size_t ws_size,
                              hipStream_t stream) {
    // ---- size-based input matching (validated) ----
    int ix = -1, iw1 = -1, ib1 = -1, iw2 = -1, ib2 = -1, irw = -1;
    for (int i = 0; i < n_in; i++) {
        int s = in_sizes[i];
        if (s == 470400 && iw1 < 0) iw1 = i;
        else if (s == 12000 && iw2 < 0) iw2 = i;
        else if (s == 96000 && irw < 0) irw = i;
        else if (s == 600) { if (ib1 < 0) ib1 = i; else if (ib2 < 0) ib2 = i; }
    }
    long bestsz = -1;
    for (int i = 0; i < n_in; i++) {
        if (i == iw1 || i == iw2 || i == irw || i == ib1 || i == ib2) continue;
        if ((long)in_sizes[i] > bestsz) { bestsz = in_sizes[i]; ix = i; }
    }
    if (ix < 0 || iw1 < 0 || ib1 < 0 || iw2 < 0 || ib2 < 0 || irw < 0) {
        ix = 0; iw1 = 1; ib1 = 2; iw2 = 3; ib2 = 4; irw = 5;
    }
    const void* x  = d_in[ix];
    const void* W1 = d_in[iw1];
    const void* b1 = d_in[ib1];
    const void* W2 = d_in[iw2];
    const void* b2 = d_in[ib2];
    const void* rw = d_in[irw];
    const int B = in_sizes[ix] / 784;
    float* out = (float*)d_out;

    float* ws   = (float*)d_ws;
    float* h1u  = ws;                                  // B*600 f32
    bfu*   rwb  = (bfu*)(ws + (size_t)B * 600);        // 96000 bf16 (48000 f32 slots)
    float* b1f  = ws + (size_t)B * 600 + 48000;        // 640 f32
    u32*   flags = (u32*)(b1f + 640);                  // 8 u32
    bfu*   Wt   = (bfu*)(flags + 8);                   // 640*800 bf16
    bfu*   xb   = Wt + 640 * 800;                      // B*800 bf16

    detect_dtype<<<1, 64, 0, stream>>>((const u32*)x, (const u32*)W1, (const u32*)b1,
                                       (const u32*)W2, (const u32*)b2, (const u32*)rw, flags);
    prep_xb<<<(B * 800 + 255) / 256, 256, 0, stream>>>(x, xb, flags, B * 800);
    prep_wt<<<(640 * 800 + 255) / 256, 256, 0, stream>>>(W1, Wt, flags);
    prep_b1<<<1, 640, 0, stream>>>(b1, b1f, flags);
    prep_rwb<<<(96000 + 255) / 256, 256, 0, stream>>>(rw, rwb, flags);
    k1m<<<dim3((B + 127) / 128, 10), 256, 0, stream>>>(xb, Wt, b1f, h1u, B);
    k2s<<<(B * 30 + 255) / 256, 256, 0, stream>>>(h1u, W2, b2, h1u, flags, B * 30);
    k3z<<<(B + 1) / 2, 160, 0, stream>>>(h1u, rwb, out, B);
}

// Round 13
// 340.468 us; speedup vs baseline: 1.2334x; 1.2334x over previous
//
#include <hip/hip_runtime.h>

// B(derived), IN_DIM=784, NUM_NETS=30, N_NODES=20, NUM_OUT=10, DIM_OUT=16, NUM_ITER=3
// Validated: size-based binding; dtype detect; k1m MFMA; k2s; k3y structure (VGPR36,
// no spill, FETCH 11MB); bf16 rwt numerics (k3z passed). k3x/k3z lesson: per-thread
// arrays >30 floats spill silently (check WRITE_SIZE ~ bytes/thread).
// R13: k3y structure + bf16 rwt (halve L2 stream); merge 4 preps into 1 launch.
// ws: h1u[B*600] f32 | rwb[96000] bf16 | b1f[640] f32 | flags[8] | Wt[640*800] bf16 | xb[B*800] bf16

typedef unsigned short bfu;
typedef unsigned int u32;
typedef __attribute__((ext_vector_type(8))) short short8;
typedef __attribute__((ext_vector_type(4))) float floatx4;

__device__ __forceinline__ float bf2f(bfu u) { union { u32 i; float f; } v; v.i = ((u32)u) << 16; return v.f; }
__device__ __forceinline__ float lo2f(u32 w) { union { u32 i; float f; } v; v.i = w << 16; return v.f; }
__device__ __forceinline__ float hi2f(u32 w) { union { u32 i; float f; } v; v.i = w & 0xffff0000u; return v.f; }
__device__ __forceinline__ float ldf(const void* p, int idx, bool b16) {
    return b16 ? bf2f(((const bfu*)p)[idx]) : ((const float*)p)[idx];
}
__device__ __forceinline__ bfu f2bf(float f) {   // RNE
    u32 u = __float_as_uint(f);
    return (bfu)((u + 0x7FFFu + ((u >> 16) & 1u)) >> 16);
}

// ---- dtype detector (validated) ----
__global__ void detect_dtype(const u32* x, const u32* W1, const u32* b1,
                             const u32* W2, const u32* b2, const u32* rw,
                             u32* flags) {
    int t = threadIdx.x;
    if (t >= 6) return;
    const u32* p = (t == 0) ? x : (t == 1) ? W1 : (t == 2) ? b1
                 : (t == 3) ? W2 : (t == 4) ? b2 : rw;
    int c = 0;
    for (int i = 0; i < 64; i++) {
        u32 e = (p[i] >> 7) & 0xFF;
        c += (e >= 64 && e <= 140) ? 1 : 0;
    }
    flags[t] = (c >= 48) ? 1u : 0u;
}

// ---- prep_all: xb | Wt | rwb | b1f in one launch (index-partitioned) ----
__global__ void prep_all(const void* x, const void* W1, const void* b1, const void* rw,
                         bfu* __restrict__ xb, bfu* __restrict__ Wt,
                         float* __restrict__ b1f, bfu* __restrict__ rwb,
                         const u32* flags, int B) {
    const int idx = blockIdx.x * 256 + threadIdx.x;
    const int nxb = B * 800;
    if (idx < nxb) {                                   // xb[B][800] bf16
        const bool b16 = flags[0] != 0;
        int b = idx / 800, kk = idx - b * 800;
        bfu v = 0;
        if (kk < 784) {
            int src = b * 784 + kk;
            v = b16 ? ((const bfu*)x)[src] : f2bf(((const float*)x)[src]);
        }
        xb[idx] = v;
        return;
    }
    int i2 = idx - nxb;
    if (i2 < 640 * 800) {                              // Wt[c][k] bf16
        const bool wb = flags[1] != 0;
        int c = i2 / 800, k = i2 - c * 800;
        bfu v = 0;
        if (c < 600 && k < 784) {
            int nn = c / 20, o = c - nn * 20;
            int src = nn * 15680 + k * 20 + o;
            v = wb ? ((const bfu*)W1)[src] : f2bf(((const float*)W1)[src]);
        }
        Wt[i2] = v;
        return;
    }
    i2 -= 640 * 800;
    if (i2 < 96000) {                                  // rwb[o][n][k][d] bf16
        const bool rb = flags[5] != 0;
        int d = i2 % 20;
        int k = (i2 / 20) % 16;
        int n = (i2 / 320) % 30;
        int o = i2 / 9600;
        int src = o * 9600 + n * 320 + d * 16 + k;
        rwb[i2] = rb ? ((const bfu*)rw)[src] : f2bf(((const float*)rw)[src]);
        return;
    }
    i2 -= 96000;
    if (i2 < 640)                                      // b1f fp32
        b1f[i2] = (i2 < 600) ? ldf(b1, i2, flags[2] != 0) : 0.f;
}

// ---------------- K1m: h1 = relu(xb @ Wt^T + b1), bf16 MFMA (validated) ----------------
__global__ __launch_bounds__(256, 4) void k1m(const bfu* __restrict__ xb, const bfu* __restrict__ Wt,
                                              const float* __restrict__ b1f,
                                              float* __restrict__ h1, int Btot) {
    __shared__ short As[128 * 40];
    __shared__ short Bs[64 * 40];
    const int tid = threadIdx.x;
    const int w = tid >> 6, lane = tid & 63;
    const int quad = lane >> 4, fl = lane & 15;
    const int m0 = blockIdx.x * 128, n0 = blockIdx.y * 64;

    floatx4 acc[2][4];
    #pragma unroll
    for (int mi = 0; mi < 2; mi++)
        #pragma unroll
        for (int ni = 0; ni < 4; ni++) acc[mi][ni] = (floatx4){0.f, 0.f, 0.f, 0.f};

    const int arow = tid >> 1, aseg = tid & 1;
    const int brow = tid >> 2, bseg = tid & 3;
    int agrow = m0 + arow; if (agrow >= Btot) agrow = Btot - 1;
    const bfu* abase = xb + (size_t)agrow * 800 + aseg * 16;
    const bfu* bbase = Wt + (size_t)(n0 + brow) * 800 + bseg * 8;

    for (int k0 = 0; k0 < 800; k0 += 32) {
        uint4 qa0 = *(const uint4*)(abase + k0);
        uint4 qa1 = *(const uint4*)(abase + k0 + 8);
        uint4 qb  = *(const uint4*)(bbase + k0);

        __syncthreads();
        *(uint4*)&As[arow * 40 + aseg * 16 + 0] = qa0;
        *(uint4*)&As[arow * 40 + aseg * 16 + 8] = qa1;
        *(uint4*)&Bs[brow * 40 + bseg * 8] = qb;
        __syncthreads();

        short8 af[2], bfr[4];
        #pragma unroll
        for (int mi = 0; mi < 2; mi++)
            af[mi] = *(const short8*)&As[(w * 32 + mi * 16 + fl) * 40 + quad * 8];
        #pragma unroll
        for (int ni = 0; ni < 4; ni++)
            bfr[ni] = *(const short8*)&Bs[(ni * 16 + fl) * 40 + quad * 8];
        #pragma unroll
        for (int mi = 0; mi < 2; mi++)
            #pragma unroll
            for (int ni = 0; ni < 4; ni++)
                acc[mi][ni] = __builtin_amdgcn_mfma_f32_16x16x32_bf16(af[mi], bfr[ni], acc[mi][ni], 0, 0, 0);
    }

    #pragma unroll
    for (int mi = 0; mi < 2; mi++) {
        #pragma unroll
        for (int ni = 0; ni < 4; ni++) {
            const int c = n0 + ni * 16 + fl;
            #pragma unroll
            for (int r = 0; r < 4; r++) {
                const int m = m0 + w * 32 + mi * 16 + quad * 4 + r;
                if (c < 600 && m < Btot)
                    h1[(size_t)m * 600 + c] = fmaxf(acc[mi][ni][r] + b1f[c], 0.f);
            }
        }
    }
}

// ---------------- K2s: u = squash(relu(h1 @ W2 + b2)), LDS-staged W2 (validated) ----------------
__global__ __launch_bounds__(256) void k2s(const float* h1, const void* W2, const void* b2,
                                           float* u, const u32* flags, int total) {
    __shared__ float W2s[12000];
    __shared__ float b2s[600];
    const bool wb = flags[3] != 0, bb = flags[4] != 0;
    const int tid = threadIdx.x;
    for (int i = tid; i < 12000; i += 256) W2s[i] = ldf(W2, i, wb);
    for (int i = tid; i < 600; i += 256) b2s[i] = ldf(b2, i, bb);
    __syncthreads();

    int t = blockIdx.x * 256 + tid;
    if (t >= total) return;          // t = b*30 + n
    const int b = t / 30, n = t - b * 30;
    const float* hp = h1 + (size_t)b * 600 + n * 20;
    float h[20];
    #pragma unroll
    for (int d4 = 0; d4 < 20; d4 += 4) {
        float4 v = *(const float4*)(hp + d4);
        h[d4] = v.x; h[d4 + 1] = v.y; h[d4 + 2] = v.z; h[d4 + 3] = v.w;
    }
    const float* wn = &W2s[n * 400];
    float o[20];
    float sq = 0.f;
    #pragma unroll
    for (int e = 0; e < 20; e++) {
        float acc = b2s[n * 20 + e];
        #pragma unroll
        for (int d = 0; d < 20; d++) acc += h[d] * wn[d * 20 + e];
        acc = fmaxf(acc, 0.f);
        o[e] = acc;
        sq += acc * acc;
    }
    float sc = (sq > 0.f) ? sqrtf(sq) / (1.f + sq) : 0.f;
    float* up = u + (size_t)b * 600 + n * 20;
    #pragma unroll
    for (int e4 = 0; e4 < 20; e4 += 4) {
        float4 v;
        v.x = o[e4] * sc; v.y = o[e4 + 1] * sc; v.z = o[e4 + 2] * sc; v.w = o[e4 + 3] * sc;
        *(float4*)(up + e4) = v;
    }
}

// ---------------- K3y2: routing; k3y structure (proven no-spill) + bf16 rwt ----------------
// 4 groups x 160 thr, 1 batch/group, pri[30] in VGPRs, u staged in LDS.
__global__ __launch_bounds__(640, 2) void k3y2(const float* __restrict__ u,
                                               const bfu* __restrict__ rwb,
                                               float* __restrict__ out, int Btot) {
    __shared__ float US[4][600];   // staged u per group
    __shared__ float L[4][300];    // logits [g][n*10+o]
    __shared__ float P[4][300];    // softmax probs
    const int tid = threadIdx.x;
    const int g = tid / 160, r = tid - g * 160;   // group, local id
    const int o = r >> 4, k = r & 15;
    const int b0 = blockIdx.x * 4;

    // stage u (coalesced float4) + init logits
    {
        const int nf4 = 150;   // 150 float4 per group
        for (int i = tid; i < 4 * nf4; i += 640) {
            int gg = i / nf4, j = i - gg * nf4;
            int bb = b0 + gg; if (bb >= Btot) bb = Btot - 1;
            *(float4*)&US[gg][j * 4] = *(const float4*)(u + (size_t)bb * 600 + j * 4);
        }
        for (int i = tid; i < 1200; i += 640) L[i / 300][i % 300] = 0.f;
    }
    __syncthreads();

    // priors: pri[n] = sum_d US[g][n*20+d] * rwb[o][n][k][d]   (bf16 rwt)
    float pri[30];
    const bfu* rp = rwb + o * 9600 + k * 20;
    #pragma unroll 2
    for (int n = 0; n < 30; n++) {
        const uint2* rq = (const uint2*)(rp + n * 320);
        float a = 0.f;
        #pragma unroll
        for (int j = 0; j < 5; j++) {
            uint2 w = rq[j];
            float4 uu = *(const float4*)&US[g][n * 20 + j * 4];
            a += lo2f(w.x) * uu.x + hi2f(w.x) * uu.y + lo2f(w.y) * uu.z + hi2f(w.y) * uu.w;
        }
        pri[n] = a;
    }

    float v = 0.f;
    for (int it = 0; it < 3; it++) {
        // phase A: P[g][n][:] = softmax(L[g][n][:]) by r<30 (n=r) per group
        if (r < 30) {
            const int n = r;
            float mx = L[g][n * 10];
            #pragma unroll
            for (int oo = 1; oo < 10; oo++) mx = fmaxf(mx, L[g][n * 10 + oo]);
            float e[10], den = 0.f;
            #pragma unroll
            for (int oo = 0; oo < 10; oo++) { e[oo] = __expf(L[g][n * 10 + oo] - mx); den += e[oo]; }
            float inv = 1.f / den;
            #pragma unroll
            for (int oo = 0; oo < 10; oo++) P[g][n * 10 + oo] = e[oo] * inv;
        }
        __syncthreads();
        // phase B: s thread-local over n; squash over k (shfl-16)
        float s = 0.f;
        #pragma unroll
        for (int n = 0; n < 30; n++) s += P[g][n * 10 + o] * pri[n];
        float q = s * s;
        q += __shfl_xor(q, 1, 16);
        q += __shfl_xor(q, 2, 16);
        q += __shfl_xor(q, 4, 16);
        q += __shfl_xor(q, 8, 16);
        v = s * sqrtf(q) / (1.f + q);
        if (it < 2) {
            // phase C: L[g][n][o] += sum_k pri*v (shfl-16; k==0 lane writes)
            #pragma unroll 5
            for (int n = 0; n < 30; n++) {
                float t = pri[n] * v;
                t += __shfl_xor(t, 1, 16);
                t += __shfl_xor(t, 2, 16);
                t += __shfl_xor(t, 4, 16);
                t += __shfl_xor(t, 8, 16);
                if (k == 0) L[g][n * 10 + o] += t;
            }
            __syncthreads();
        }
    }
    if ((b0 + g) < Btot) out[(size_t)(b0 + g) * 160 + r] = v;
}

extern "C" void kernel_launch(void* const* d_in, const int* in_sizes, int n_in,
                              void* d_out, int out_size, void* d_ws, size_t ws_size,
                              hipStream_t stream) {
    // ---- size-based input matching (validated) ----
    int ix = -1, iw1 = -1, ib1 = -1, iw2 = -1, ib2 = -1, irw = -1;
    for (int i = 0; i < n_in; i++) {
        int s = in_sizes[i];
        if (s == 470400 && iw1 < 0) iw1 = i;
        else if (s == 12000 && iw2 < 0) iw2 = i;
        else if (s == 96000 && irw < 0) irw = i;
        else if (s == 600) { if (ib1 < 0) ib1 = i; else if (ib2 < 0) ib2 = i; }
    }
    long bestsz = -1;
    for (int i = 0; i < n_in; i++) {
        if (i == iw1 || i == iw2 || i == irw || i == ib1 || i == ib2) continue;
        if ((long)in_sizes[i] > bestsz) { bestsz = in_sizes[i]; ix = i; }
    }
    if (ix < 0 || iw1 < 0 || ib1 < 0 || iw2 < 0 || ib2 < 0 || irw < 0) {
        ix = 0; iw1 = 1; ib1 = 2; iw2 = 3; ib2 = 4; irw = 5;
    }
    const void* x  = d_in[ix];
    const void* W1 = d_in[iw1];
    const void* b1 = d_in[ib1];
    const void* W2 = d_in[iw2];
    const void* b2 = d_in[ib2];
    const void* rw = d_in[irw];
    const int B = in_sizes[ix] / 784;
    float* out = (float*)d_out;

    float* ws   = (float*)d_ws;
    float* h1u  = ws;                                  // B*600 f32
    bfu*   rwb  = (bfu*)(ws + (size_t)B * 600);        // 96000 bf16
    float* b1f  = ws + (size_t)B * 600 + 48000;        // 640 f32
    u32*   flags = (u32*)(b1f + 640);                  // 8 u32
    bfu*   Wt   = (bfu*)(flags + 8);                   // 640*800 bf16
    bfu*   xb   = Wt + 640 * 800;                      // B*800 bf16

    const int prep_total = B * 800 + 640 * 800 + 96000 + 640;

    detect_dtype<<<1, 64, 0, stream>>>((const u32*)x, (const u32*)W1, (const u32*)b1,
                                       (const u32*)W2, (const u32*)b2, (const u32*)rw, flags);
    prep_all<<<(prep_total + 255) / 256, 256, 0, stream>>>(x, W1, b1, rw, xb, Wt, b1f, rwb, flags, B);
    k1m<<<dim3((B + 127) / 128, 10), 256, 0, stream>>>(xb, Wt, b1f, h1u, B);
    k2s<<<(B * 30 + 255) / 256, 256, 0, stream>>>(h1u, W2, b2, h1u, flags, B * 30);
    k3y2<<<(B + 3) / 4, 640, 0, stream>>>(h1u, rwb, out, B);
}

// Round 14
// 272.932 us; speedup vs baseline: 1.5387x; 1.2474x over previous
//
#include <hip/hip_runtime.h>

// B(derived), IN_DIM=784, NUM_NETS=30, N_NODES=20, NUM_OUT=10, DIM_OUT=16, NUM_ITER=3
// Validated: size-based binding; dtype detect; k1m MFMA; k2s; k3y2 routing (202us,
// DS-pipe/VALU-bound on the priors dot). R14: priors -> MFMA GEMM (k2p) on bf16 u,
// routing-only k3r reads bf16 priors coalesced. ws needs ~129MB; host falls back to
// the proven k2s+k3y2 path (34MB) if ws_size is insufficient (fixed per-call -> graph-safe).

typedef unsigned short bfu;
typedef unsigned int u32;
typedef __attribute__((ext_vector_type(8))) short short8;
typedef __attribute__((ext_vector_type(4))) float floatx4;

__device__ __forceinline__ float bf2f(bfu u) { union { u32 i; float f; } v; v.i = ((u32)u) << 16; return v.f; }
__device__ __forceinline__ float lo2f(u32 w) { union { u32 i; float f; } v; v.i = w << 16; return v.f; }
__device__ __forceinline__ float hi2f(u32 w) { union { u32 i; float f; } v; v.i = w & 0xffff0000u; return v.f; }
__device__ __forceinline__ float ldf(const void* p, int idx, bool b16) {
    return b16 ? bf2f(((const bfu*)p)[idx]) : ((const float*)p)[idx];
}
__device__ __forceinline__ bfu f2bf(float f) {   // RNE
    u32 u = __float_as_uint(f);
    return (bfu)((u + 0x7FFFu + ((u >> 16) & 1u)) >> 16);
}

// ---- dtype detector (validated) ----
__global__ void detect_dtype(const u32* x, const u32* W1, const u32* b1,
                             const u32* W2, const u32* b2, const u32* rw,
                             u32* flags) {
    int t = threadIdx.x;
    if (t >= 6) return;
    const u32* p = (t == 0) ? x : (t == 1) ? W1 : (t == 2) ? b1
                 : (t == 3) ? W2 : (t == 4) ? b2 : rw;
    int c = 0;
    for (int i = 0; i < 64; i++) {
        u32 e = (p[i] >> 7) & 0xFF;
        c += (e >= 64 && e <= 140) ? 1 : 0;
    }
    flags[t] = (c >= 48) ? 1u : 0u;
}

// ---- prep_all: xb | Wt | rwb | b1f (+ rwn if mode==0), index-partitioned ----
__global__ void prep_all(const void* x, const void* W1, const void* b1, const void* rw,
                         bfu* __restrict__ xb, bfu* __restrict__ Wt,
                         float* __restrict__ b1f, bfu* __restrict__ rwb,
                         bfu* __restrict__ rwn,
                         const u32* flags, int B, int mode) {
    const int idx = blockIdx.x * 256 + threadIdx.x;
    const int nxb = B * 800;
    if (idx < nxb) {                                   // xb[B][800] bf16
        const bool b16 = flags[0] != 0;
        int b = idx / 800, kk = idx - b * 800;
        bfu v = 0;
        if (kk < 784) {
            int src = b * 784 + kk;
            v = b16 ? ((const bfu*)x)[src] : f2bf(((const float*)x)[src]);
        }
        xb[idx] = v;
        return;
    }
    int i2 = idx - nxb;
    if (i2 < 640 * 800) {                              // Wt[c][k] bf16
        const bool wb = flags[1] != 0;
        int c = i2 / 800, k = i2 - c * 800;
        bfu v = 0;
        if (c < 600 && k < 784) {
            int nn = c / 20, o = c - nn * 20;
            int src = nn * 15680 + k * 20 + o;
            v = wb ? ((const bfu*)W1)[src] : f2bf(((const float*)W1)[src]);
        }
        Wt[i2] = v;
        return;
    }
    i2 -= 640 * 800;
    if (i2 < 96000) {                                  // rwb[o][n][k][d] bf16 (fallback k3y2)
        const bool rb = flags[5] != 0;
        int d = i2 % 20;
        int k = (i2 / 20) % 16;
        int n = (i2 / 320) % 30;
        int o = i2 / 9600;
        int src = o * 9600 + n * 320 + d * 16 + k;
        rwb[i2] = rb ? ((const bfu*)rw)[src] : f2bf(((const float*)rw)[src]);
        return;
    }
    i2 -= 96000;
    if (i2 < 640) {                                    // b1f fp32
        b1f[i2] = (i2 < 600) ? ldf(b1, i2, flags[2] != 0) : 0.f;
        return;
    }
    i2 -= 640;
    if (mode == 0 && i2 < 153600) {                    // rwn[n][col=o*16+k][dd<32] bf16, K-pad
        const bool rb = flags[5] != 0;
        int dd = i2 % 32;
        int col = (i2 / 32) % 160;
        int n = i2 / 5120;
        bfu v = 0;
        if (dd < 20) {
            int o = col / 16, kk = col % 16;
            int src = o * 9600 + n * 320 + dd * 16 + kk;
            v = rb ? ((const bfu*)rw)[src] : f2bf(((const float*)rw)[src]);
        }
        rwn[i2] = v;
    }
}

// ---------------- K1m: h1 = relu(xb @ Wt^T + b1), bf16 MFMA (validated) ----------------
__global__ __launch_bounds__(256, 4) void k1m(const bfu* __restrict__ xb, const bfu* __restrict__ Wt,
                                              const float* __restrict__ b1f,
                                              float* __restrict__ h1, int Btot) {
    __shared__ short As[128 * 40];
    __shared__ short Bs[64 * 40];
    const int tid = threadIdx.x;
    const int w = tid >> 6, lane = tid & 63;
    const int quad = lane >> 4, fl = lane & 15;
    const int m0 = blockIdx.x * 128, n0 = blockIdx.y * 64;

    floatx4 acc[2][4];
    #pragma unroll
    for (int mi = 0; mi < 2; mi++)
        #pragma unroll
        for (int ni = 0; ni < 4; ni++) acc[mi][ni] = (floatx4){0.f, 0.f, 0.f, 0.f};

    const int arow = tid >> 1, aseg = tid & 1;
    const int brow = tid >> 2, bseg = tid & 3;
    int agrow = m0 + arow; if (agrow >= Btot) agrow = Btot - 1;
    const bfu* abase = xb + (size_t)agrow * 800 + aseg * 16;
    const bfu* bbase = Wt + (size_t)(n0 + brow) * 800 + bseg * 8;

    for (int k0 = 0; k0 < 800; k0 += 32) {
        uint4 qa0 = *(const uint4*)(abase + k0);
        uint4 qa1 = *(const uint4*)(abase + k0 + 8);
        uint4 qb  = *(const uint4*)(bbase + k0);

        __syncthreads();
        *(uint4*)&As[arow * 40 + aseg * 16 + 0] = qa0;
        *(uint4*)&As[arow * 40 + aseg * 16 + 8] = qa1;
        *(uint4*)&Bs[brow * 40 + bseg * 8] = qb;
        __syncthreads();

        short8 af[2], bfr[4];
        #pragma unroll
        for (int mi = 0; mi < 2; mi++)
            af[mi] = *(const short8*)&As[(w * 32 + mi * 16 + fl) * 40 + quad * 8];
        #pragma unroll
        for (int ni = 0; ni < 4; ni++)
            bfr[ni] = *(const short8*)&Bs[(ni * 16 + fl) * 40 + quad * 8];
        #pragma unroll
        for (int mi = 0; mi < 2; mi++)
            #pragma unroll
            for (int ni = 0; ni < 4; ni++)
                acc[mi][ni] = __builtin_amdgcn_mfma_f32_16x16x32_bf16(af[mi], bfr[ni], acc[mi][ni], 0, 0, 0);
    }

    #pragma unroll
    for (int mi = 0; mi < 2; mi++) {
        #pragma unroll
        for (int ni = 0; ni < 4; ni++) {
            const int c = n0 + ni * 16 + fl;
            #pragma unroll
            for (int r = 0; r < 4; r++) {
                const int m = m0 + w * 32 + mi * 16 + quad * 4 + r;
                if (c < 600 && m < Btot)
                    h1[(size_t)m * 600 + c] = fmaxf(acc[mi][ni][r] + b1f[c], 0.f);
            }
        }
    }
}

// ---------------- K2 core (validated math) ----------------
__device__ __forceinline__ void k2_core(const float* hp, const float* wn, const float* bn,
                                        float* o, float& sc) {
    float h[20];
    #pragma unroll
    for (int d4 = 0; d4 < 20; d4 += 4) {
        float4 v = *(const float4*)(hp + d4);
        h[d4] = v.x; h[d4 + 1] = v.y; h[d4 + 2] = v.z; h[d4 + 3] = v.w;
    }
    float sq = 0.f;
    #pragma unroll
    for (int e = 0; e < 20; e++) {
        float acc = bn[e];
        #pragma unroll
        for (int d = 0; d < 20; d++) acc += h[d] * wn[d * 20 + e];
        acc = fmaxf(acc, 0.f);
        o[e] = acc;
        sq += acc * acc;
    }
    sc = (sq > 0.f) ? sqrtf(sq) / (1.f + sq) : 0.f;
}

// K2b (main): u -> ub32[b][n][32] bf16, zero-padded
__global__ __launch_bounds__(256) void k2b(const float* h1, const void* W2, const void* b2,
                                           bfu* __restrict__ ub32, const u32* flags, int total) {
    __shared__ float W2s[12000];
    __shared__ float b2s[600];
    const bool wb = flags[3] != 0, bb = flags[4] != 0;
    const int tid = threadIdx.x;
    for (int i = tid; i < 12000; i += 256) W2s[i] = ldf(W2, i, wb);
    for (int i = tid; i < 600; i += 256) b2s[i] = ldf(b2, i, bb);
    __syncthreads();

    int t = blockIdx.x * 256 + tid;
    if (t >= total) return;          // t = b*30 + n
    const int b = t / 30, n = t - b * 30;
    float o[20], sc;
    k2_core(h1 + (size_t)b * 600 + n * 20, &W2s[n * 400], &b2s[n * 20], o, sc);

    u32 wbuf[16];
    #pragma unroll
    for (int j = 0; j < 10; j++)
        wbuf[j] = (u32)f2bf(o[2 * j] * sc) | ((u32)f2bf(o[2 * j + 1] * sc) << 16);
    #pragma unroll
    for (int j = 10; j < 16; j++) wbuf[j] = 0;
    uint4* dst = (uint4*)(ub32 + ((size_t)b * 30 + n) * 32);
    dst[0] = *(uint4*)&wbuf[0];
    dst[1] = *(uint4*)&wbuf[4];
    dst[2] = *(uint4*)&wbuf[8];
    dst[3] = *(uint4*)&wbuf[12];
}

// K2s (fallback, validated): u fp32 in place
__global__ __launch_bounds__(256) void k2s(const float* h1, const void* W2, const void* b2,
                                           float* u, const u32* flags, int total) {
    __shared__ float W2s[12000];
    __shared__ float b2s[600];
    const bool wb = flags[3] != 0, bb = flags[4] != 0;
    const int tid = threadIdx.x;
    for (int i = tid; i < 12000; i += 256) W2s[i] = ldf(W2, i, wb);
    for (int i = tid; i < 600; i += 256) b2s[i] = ldf(b2, i, bb);
    __syncthreads();

    int t = blockIdx.x * 256 + tid;
    if (t >= total) return;
    const int b = t / 30, n = t - b * 30;
    float o[20], sc;
    k2_core(h1 + (size_t)b * 600 + n * 20, &W2s[n * 400], &b2s[n * 20], o, sc);
    float* up = u + (size_t)b * 600 + n * 20;
    #pragma unroll
    for (int e4 = 0; e4 < 20; e4 += 4) {
        float4 v;
        v.x = o[e4] * sc; v.y = o[e4 + 1] * sc; v.z = o[e4 + 2] * sc; v.w = o[e4 + 3] * sc;
        *(float4*)(up + e4) = v;
    }
}

// ---------------- K2p: priors GEMM via MFMA (main) ----------------
// grid (ceil(B/128), 30); block 256 = 4 waves; wave w: rows w*32..+31; single K=32 step.
// pri[b][n*160 + o*16+k] bf16.
__global__ __launch_bounds__(256) void k2p(const bfu* __restrict__ ub32,
                                           const bfu* __restrict__ rwn,
                                           bfu* __restrict__ pri, int Btot) {
    const int tid = threadIdx.x;
    const int w = tid >> 6, lane = tid & 63;
    const int quad = lane >> 4, fl = lane & 15;
    const int n = blockIdx.y;
    const int b0 = blockIdx.x * 128;

    short8 bfr[10];
    #pragma unroll
    for (int nj = 0; nj < 10; nj++)
        bfr[nj] = *(const short8*)(rwn + ((size_t)n * 160 + nj * 16 + fl) * 32 + quad * 8);

    #pragma unroll
    for (int mi = 0; mi < 2; mi++) {
        int m = b0 + w * 32 + mi * 16 + fl;
        int mc = (m < Btot) ? m : Btot - 1;
        short8 af = *(const short8*)(ub32 + ((size_t)mc * 30 + n) * 32 + quad * 8);
        #pragma unroll
        for (int nj = 0; nj < 10; nj++) {
            floatx4 acc = (floatx4){0.f, 0.f, 0.f, 0.f};
            acc = __builtin_amdgcn_mfma_f32_16x16x32_bf16(af, bfr[nj], acc, 0, 0, 0);
            #pragma unroll
            for (int r = 0; r < 4; r++) {
                int mr = b0 + w * 32 + mi * 16 + quad * 4 + r;
                if (mr < Btot)
                    pri[(size_t)mr * 4800 + n * 160 + nj * 16 + fl] = f2bf(acc[r]);
            }
        }
    }
}

// ---------------- K3r: routing-only (main); phases verbatim from validated k3y2 ----------------
__global__ __launch_bounds__(640, 2) void k3r(const bfu* __restrict__ pri_buf,
                                              float* __restrict__ out, int Btot) {
    __shared__ float L[4][300];
    __shared__ float P[4][300];
    const int tid = threadIdx.x;
    const int g = tid / 160, r = tid - g * 160;
    const int o = r >> 4, k = r & 15;
    const int b0 = blockIdx.x * 4;
    int bb = b0 + g; if (bb >= Btot) bb = Btot - 1;

    const bfu* pb = pri_buf + (size_t)bb * 4800 + r;
    float pri[30];
    #pragma unroll
    for (int n = 0; n < 30; n++) pri[n] = bf2f(pb[n * 160]);

    for (int i = tid; i < 1200; i += 640) L[i / 300][i % 300] = 0.f;
    __syncthreads();

    float v = 0.f;
    for (int it = 0; it < 3; it++) {
        if (r < 30) {
            const int n = r;
            float mx = L[g][n * 10];
            #pragma unroll
            for (int oo = 1; oo < 10; oo++) mx = fmaxf(mx, L[g][n * 10 + oo]);
            float e[10], den = 0.f;
            #pragma unroll
            for (int oo = 0; oo < 10; oo++) { e[oo] = __expf(L[g][n * 10 + oo] - mx); den += e[oo]; }
            float inv = 1.f / den;
            #pragma unroll
            for (int oo = 0; oo < 10; oo++) P[g][n * 10 + oo] = e[oo] * inv;
        }
        __syncthreads();
        float s = 0.f;
        #pragma unroll
        for (int n = 0; n < 30; n++) s += P[g][n * 10 + o] * pri[n];
        float q = s * s;
        q += __shfl_xor(q, 1, 16);
        q += __shfl_xor(q, 2, 16);
        q += __shfl_xor(q, 4, 16);
        q += __shfl_xor(q, 8, 16);
        v = s * sqrtf(q) / (1.f + q);
        if (it < 2) {
            #pragma unroll 5
            for (int n = 0; n < 30; n++) {
                float t = pri[n] * v;
                t += __shfl_xor(t, 1, 16);
                t += __shfl_xor(t, 2, 16);
                t += __shfl_xor(t, 4, 16);
                t += __shfl_xor(t, 8, 16);
                if (k == 0) L[g][n * 10 + o] += t;
            }
            __syncthreads();
        }
    }
    if ((b0 + g) < Btot) out[(size_t)(b0 + g) * 160 + r] = v;
}

// ---------------- K3y2 (fallback, validated @202us) ----------------
__global__ __launch_bounds__(640, 2) void k3y2(const float* __restrict__ u,
                                               const bfu* __restrict__ rwb,
                                               float* __restrict__ out, int Btot) {
    __shared__ float US[4][600];
    __shared__ float L[4][300];
    __shared__ float P[4][300];
    const int tid = threadIdx.x;
    const int g = tid / 160, r = tid - g * 160;
    const int o = r >> 4, k = r & 15;
    const int b0 = blockIdx.x * 4;

    {
        const int nf4 = 150;
        for (int i = tid; i < 4 * nf4; i += 640) {
            int gg = i / nf4, j = i - gg * nf4;
            int bb = b0 + gg; if (bb >= Btot) bb = Btot - 1;
            *(float4*)&US[gg][j * 4] = *(const float4*)(u + (size_t)bb * 600 + j * 4);
        }
        for (int i = tid; i < 1200; i += 640) L[i / 300][i % 300] = 0.f;
    }
    __syncthreads();

    float pri[30];
    const bfu* rp = rwb + o * 9600 + k * 20;
    #pragma unroll 2
    for (int n = 0; n < 30; n++) {
        const uint2* rq = (const uint2*)(rp + n * 320);
        float a = 0.f;
        #pragma unroll
        for (int j = 0; j < 5; j++) {
            uint2 w = rq[j];
            float4 uu = *(const float4*)&US[g][n * 20 + j * 4];
            a += lo2f(w.x) * uu.x + hi2f(w.x) * uu.y + lo2f(w.y) * uu.z + hi2f(w.y) * uu.w;
        }
        pri[n] = a;
    }

    float v = 0.f;
    for (int it = 0; it < 3; it++) {
        if (r < 30) {
            const int n = r;
            float mx = L[g][n * 10];
            #pragma unroll
            for (int oo = 1; oo < 10; oo++) mx = fmaxf(mx, L[g][n * 10 + oo]);
            float e[10], den = 0.f;
            #pragma unroll
            for (int oo = 0; oo < 10; oo++) { e[oo] = __expf(L[g][n * 10 + oo] - mx); den += e[oo]; }
            float inv = 1.f / den;
            #pragma unroll
            for (int oo = 0; oo < 10; oo++) P[g][n * 10 + oo] = e[oo] * inv;
        }
        __syncthreads();
        float s = 0.f;
        #pragma unroll
        for (int n = 0; n < 30; n++) s += P[g][n * 10 + o] * pri[n];
        float q = s * s;
        q += __shfl_xor(q, 1, 16);
        q += __shfl_xor(q, 2, 16);
        q += __shfl_xor(q, 4, 16);
        q += __shfl_xor(q, 8, 16);
        v = s * sqrtf(q) / (1.f + q);
        if (it < 2) {
            #pragma unroll 5
            for (int n = 0; n < 30; n++) {
                float t = pri[n] * v;
                t += __shfl_xor(t, 1, 16);
                t += __shfl_xor(t, 2, 16);
                t += __shfl_xor(t, 4, 16);
                t += __shfl_xor(t, 8, 16);
                if (k == 0) L[g][n * 10 + o] += t;
            }
            __syncthreads();
        }
    }
    if ((b0 + g) < Btot) out[(size_t)(b0 + g) * 160 + r] = v;
}

extern "C" void kernel_launch(void* const* d_in, const int* in_sizes, int n_in,
                              void* d_out, int out_size, void* d_ws, size_t ws_size,
                              hipStream_t stream) {
    // ---- size-based input matching (validated) ----
    int ix = -1, iw1 = -1, ib1 = -1, iw2 = -1, ib2 = -1, irw = -1;
    for (int i = 0; i < n_in; i++) {
        int s = in_sizes[i];
        if (s == 470400 && iw1 < 0) iw1 = i;
        else if (s == 12000 && iw2 < 0) iw2 = i;
        else if (s == 96000 && irw < 0) irw = i;
        else if (s == 600) { if (ib1 < 0) ib1 = i; else if (ib2 < 0) ib2 = i; }
    }
    long bestsz = -1;
    for (int i = 0; i < n_in; i++) {
        if (i == iw1 || i == iw2 || i == irw || i == ib1 || i == ib2) continue;
        if ((long)in_sizes[i] > bestsz) { bestsz = in_sizes[i]; ix = i; }
    }
    if (ix < 0 || iw1 < 0 || ib1 < 0 || iw2 < 0 || ib2 < 0 || irw < 0) {
        ix = 0; iw1 = 1; ib1 = 2; iw2 = 3; ib2 = 4; irw = 5;
    }
    const void* x  = d_in[ix];
    const void* W1 = d_in[iw1];
    const void* b1 = d_in[ib1];
    const void* W2 = d_in[iw2];
    const void* b2 = d_in[ib2];
    const void* rw = d_in[irw];
    const int B = in_sizes[ix] / 784;
    float* out = (float*)d_out;

    // ---- ws layout (byte offsets, all 16B-aligned) ----
    char* base = (char*)d_ws;
    size_t off = 0;
    float* h1u  = (float*)(base + off); off += (size_t)B * 2400;       // B*600 f32
    float* b1f  = (float*)(base + off); off += 2560;                   // 640 f32
    u32*  flags = (u32*)(base + off);   off += 32;                     // 8 u32
    bfu*   Wt   = (bfu*)(base + off);   off += 1024000;                // 640*800 bf16
    bfu*   xb   = (bfu*)(base + off);   off += (size_t)B * 1600;       // B*800 bf16
    bfu*   rwb  = (bfu*)(base + off);   off += 192000;                 // 96000 bf16
    size_t fb_bytes = off;
    bfu*   rwn  = (bfu*)(base + off);   off += 307200;                 // 30*160*32 bf16
    bfu*   ub32 = (bfu*)(base + off);   off += (size_t)B * 1920;       // B*30*32 bf16
    bfu*   pri  = (bfu*)(base + off);   off += (size_t)B * 9600;       // B*4800 bf16
    size_t main_bytes = off;

    const int mode = (ws_size >= main_bytes) ? 0 : 1;   // fixed per-call -> graph-safe
    const int prep_total = B * 800 + 640 * 800 + 96000 + 640 + (mode == 0 ? 153600 : 0);

    detect_dtype<<<1, 64, 0, stream>>>((const u32*)x, (const u32*)W1, (const u32*)b1,
                                       (const u32*)W2, (const u32*)b2, (const u32*)rw, flags);
    prep_all<<<(prep_total + 255) / 256, 256, 0, stream>>>(x, W1, b1, rw, xb, Wt, b1f,
                                                           rwb, rwn, flags, B, mode);
    k1m<<<dim3((B + 127) / 128, 10), 256, 0, stream>>>(xb, Wt, b1f, h1u, B);
    if (mode == 0) {
        k2b<<<(B * 30 + 255) / 256, 256, 0, stream>>>(h1u, W2, b2, ub32, flags, B * 30);
        k2p<<<dim3((B + 127) / 128, 30), 256, 0, stream>>>(ub32, rwn, pri, B);
        k3r<<<(B + 3) / 4, 640, 0, stream>>>(pri, out, B);
    } else {
        (void)fb_bytes;
        k2s<<<(B * 30 + 255) / 256, 256, 0, stream>>>(h1u, W2, b2, h1u, flags, B * 30);
        k3y2<<<(B + 3) / 4, 640, 0, stream>>>(h1u, rwb, out, B);
    }
}